// Round 10
// baseline (436.432 us; speedup 1.0000x reference)
//
#include <hip/hip_runtime.h>

#define B_ 64
#define T_ 512
#define D_ 1024
#define C_ 32
#define KCH 64                // k-chunk for k_logits LDS tiling
#define NEG_INF (-1e30f)

__device__ __forceinline__ float bcast0(float v) {
  return __uint_as_float(__builtin_amdgcn_readfirstlane(__float_as_uint(v)));
}

// DPP cross-lane mov (VALU pipe, exact data movement; primitive validated by
// R9's partial pass). ctrl is a compile-time constant at every use.
#define DPPF(x, ctrl) \
  __uint_as_float(__builtin_amdgcn_update_dpp(0, (int)__float_as_uint(x), (ctrl), 0xF, 0xF, true))
#define CTL_X1 0xB1   // quad_perm [1,0,3,2] : lane ^= 1
#define CTL_X2 0x4E   // quad_perm [2,3,0,1] : lane ^= 2
#define CTL_X7 0x141  // row_half_mirror     : lane ^= 7
#define CTL_XF 0x140  // row_mirror          : lane ^= 15

// Butterfly all-gather: after BFLY(x, val), lane j's reg val[r] holds
// x from lane (j ^ MU[r]) — a LANE-DEPENDENT permutation (R9's bug was
// assuming lane-independence). MU[r] for stage masks {16,1,2,7,15}:
#define MU_INIT {0,16,1,17,2,18,3,19,7,23,6,22,5,21,4,20, \
                 15,31,14,30,13,29,12,28,8,24,9,25,10,26,11,27}

#define BFLY(x, val)                                                    \
  {                                                                     \
    val[0] = (x);                                                       \
    val[1] = __shfl_xor((x), 16);                                       \
    val[2] = DPPF(val[0], CTL_X1);  val[3] = DPPF(val[1], CTL_X1);      \
    _Pragma("unroll")                                                   \
    for (int k_ = 0; k_ < 4; ++k_) val[4 + k_] = DPPF(val[k_], CTL_X2); \
    _Pragma("unroll")                                                   \
    for (int k_ = 0; k_ < 8; ++k_) val[8 + k_] = DPPF(val[k_], CTL_X7); \
    _Pragma("unroll")                                                   \
    for (int k_ = 0; k_ < 16; ++k_) val[16 + k_] = DPPF(val[k_], CTL_XF); \
  }

// ---------------- logits = vectors @ W^T + b (f32, sequential-k fma chain) ----------------
// R7 version (kept): BM=64, grid 512 -> 2 blocks/CU. LDS-tiled, coalesced.
__global__ __launch_bounds__(256) void k_logits(const float* __restrict__ vec,
                                                const float* __restrict__ W,
                                                const float* __restrict__ bias,
                                                float* __restrict__ out) {
  __shared__ __align__(16) float vt[64][KCH + 4];   // 17408 B
  __shared__ __align__(16) float wt[32][KCH + 4];   //  8704 B
  const int tid = threadIdx.x;
  const int cg = tid & 7;
  const int rg = tid >> 3;
  const int r0 = blockIdx.x * 64;
  const int sr = tid >> 4;
  const int sq = tid & 15;
  const int wr = tid >> 3;
  const int wq = tid & 7;
  float acc[2][4];
#pragma unroll
  for (int a = 0; a < 2; ++a)
#pragma unroll
    for (int bb = 0; bb < 4; ++bb) acc[a][bb] = 0.f;

  for (int c = 0; c < D_ / KCH; ++c) {
    const int k0 = c * KCH;
    __syncthreads();
#pragma unroll
    for (int p = 0; p < 4; ++p) {
      const int r = p * 16 + sr;
      float4 v = *(const float4*)(vec + (size_t)(r0 + r) * D_ + k0 + sq * 4);
      *(float4*)&vt[r][sq * 4] = v;
    }
    {
      float4 a = *(const float4*)(W + (size_t)wr * D_ + k0 + wq * 4);
      float4 b2 = *(const float4*)(W + (size_t)wr * D_ + k0 + (wq + 8) * 4);
      *(float4*)&wt[wr][wq * 4] = a;
      *(float4*)&wt[wr][(wq + 8) * 4] = b2;
    }
    __syncthreads();
#pragma unroll 2
    for (int k = 0; k < KCH; k += 4) {
      float4 v[2], w[4];
#pragma unroll
      for (int rr = 0; rr < 2; ++rr) v[rr] = *(const float4*)&vt[rg + rr * 32][k];
#pragma unroll
      for (int cc = 0; cc < 4; ++cc) w[cc] = *(const float4*)&wt[cg + cc * 8][k];
#pragma unroll
      for (int rr = 0; rr < 2; ++rr)
#pragma unroll
        for (int cc = 0; cc < 4; ++cc) {
          acc[rr][cc] = fmaf(v[rr].x, w[cc].x, acc[rr][cc]);
          acc[rr][cc] = fmaf(v[rr].y, w[cc].y, acc[rr][cc]);
          acc[rr][cc] = fmaf(v[rr].z, w[cc].z, acc[rr][cc]);
          acc[rr][cc] = fmaf(v[rr].w, w[cc].w, acc[rr][cc]);
        }
    }
  }
#pragma unroll
  for (int rr = 0; rr < 2; ++rr) {
    const size_t row = (size_t)(r0 + rg + rr * 32);
#pragma unroll
    for (int cc = 0; cc < 4; ++cc) {
      const int c = cg + cc * 8;
      out[row * C_ + c] = acc[rr][cc] + bias[c];  // b32: out base only 4B-aligned
    }
  }
}

// ---------------- CRF: forward(+score) and Viterbi(+backtrace) ----------------
// grid 128 x 64 threads (one wave64 per block -> LDS in-order, no barriers).
// R10: pure-VALU serial chain. State broadcast via DPP butterfly; the
// lane-dependent permutation is paired with PERMUTED COEFFICIENTS gathered at
// setup: TT2[r]=trans[(j^MU[r])*C+j] (ET2 analog for forward). So the
// candidate SET {delta[i]+trans[i][j]} is bit-identical to np's inner[:,j];
// fmax is exactly associative/commutative -> values-only max is bit-exact ->
// the delta ring is bit-identical to R8's (harness-validated). Backpointers
// come from R8's validated phase2 (parallel descending '>=' scan in ORIGINAL
// index order == np.argmax first-index ties). No LDS read on the serial
// chain: logits and mask are chunk-copied to registers; ring write is
// fire-and-forget.
__global__ __launch_bounds__(64) void k_crf(const float* __restrict__ lg,
                                            const int* __restrict__ mask,
                                            const int* __restrict__ tgt,
                                            const float* __restrict__ trans,
                                            const float* __restrict__ st,
                                            const float* __restrict__ et,
                                            float* __restrict__ wsp,
                                            float* __restrict__ tags_out,
                                            float* __restrict__ path_out) {
  __shared__ __align__(16) float dsh[256 * C_];  // delta ring (role1), 32KB
  __shared__ float s0_sh[T_];                    // role0 scale record
  __shared__ int mk_sh[T_];
  __shared__ unsigned char bp[(T_ - 1) * C_];
  __shared__ unsigned char tagb[T_];
  __shared__ unsigned char c8[64 * C_];
  __shared__ int btag[64];

  const int tid = threadIdx.x;
  const int b = blockIdx.x & 63;
  const int role = blockIdx.x >> 6;
  const int j = tid & 31;   // lanes 32-63 duplicate lanes 0-31 throughout
  const int h = tid >> 5;
  const float* L = lg + (size_t)b * T_ * C_;
  const int* mk = mask + b * T_;

  {
    int4 m0 = *(const int4*)(mk + tid * 4);
    int4 m1 = *(const int4*)(mk + 256 + tid * 4);
    *(int4*)&mk_sh[tid * 4] = m0;
    *(int4*)&mk_sh[256 + tid * 4] = m1;
  }

  constexpr int MU[32] = MU_INIT;

  // chunk-0 logits rows 0..15, column j, in registers
  float Lc[16], Ln[16];
#pragma unroll
  for (int i = 0; i < 16; ++i) Lc[i] = L[i * C_ + j];

  if (role == 0) {
    // ================= forward (scaled-prob, register state) + score ========
    float ET2[32];
#pragma unroll
    for (int r = 0; r < 32; ++r) ET2[r] = __expf(trans[(j ^ MU[r]) * C_ + j]);
    float Fc[16];
#pragma unroll
    for (int i = 0; i < 16; ++i) Fc[i] = __expf(Lc[i] - bcast0(Lc[i]));
    const float a0j = st[j] + Lc[0];
    const float m0 = bcast0(a0j);
    float vp = __expf(a0j - m0);       // lanes j and j+32 identical
    for (int c = 0; c < 32; ++c) {
      int Mc[16];
#pragma unroll
      for (int i = 0; i < 16; ++i) Mc[i] = mk_sh[c * 16 + i];  // off-chain copy
      if (c < 31) {
#pragma unroll
        for (int i = 0; i < 16; ++i) Ln[i] = L[((c + 1) * 16 + i) * C_ + j];
      }
#pragma unroll
      for (int i = 0; i < 16; ++i) {
        if (i == 0 && c == 0) continue;          // t=0 is the init
        const int t = c * 16 + i;
        const int mc = Mc[i];
        float val[32];
        BFLY(vp, val);
        // sum over the SAME term set as np's s_j, permuted association:
        // val[r]*ET2[r] = p[i_r]*exp(trans[i_r][j]), i_r = j^MU[r].
        float s0 = val[0] * ET2[0], s1 = val[1] * ET2[1];
        float s2 = val[2] * ET2[2], s3 = val[3] * ET2[3];
#pragma unroll
        for (int g = 1; g < 8; ++g) {
          s0 = fmaf(val[4 * g + 0], ET2[4 * g + 0], s0);
          s1 = fmaf(val[4 * g + 1], ET2[4 * g + 1], s1);
          s2 = fmaf(val[4 * g + 2], ET2[4 * g + 2], s2);
          s3 = fmaf(val[4 * g + 3], ET2[4 * g + 3], s3);
        }
        const float sv = (s0 + s1) + (s2 + s3);  // lane j -> correct s_j
        const float s0b = bcast0(sv);            // lane 0 (j=0) -> s_0
        const float r = __builtin_amdgcn_rcpf(s0b);
        const float pn = sv * r * Fc[i];
        vp = (mc > 0) ? pn : vp;
        if (tid == 0) s0_sh[t] = (mc > 0) ? s0b : 1.0f;
      }
      if (c < 31) {
#pragma unroll
        for (int i = 0; i < 16; ++i) { Lc[i] = Ln[i]; Fc[i] = __expf(Lc[i] - bcast0(Lc[i])); }
      }
    }
    // reconstruct m_T = m0 + sum_{t>=1, masked}(log s0_t + lc_t[0])  (R5/R8)
    float lsum = 0.f, csum = 0.f;
#pragma unroll
    for (int kk = 0; kk < 8; ++kk) {
      const int t = tid + kk * 64;
      if (t >= 1) {
        lsum += __logf(s0_sh[t]);  // 1 when masked-out -> log 0
        if (mk_sh[t] > 0) csum += L[(size_t)t * C_];
      }
    }
#pragma unroll
    for (int d = 32; d; d >>= 1) { lsum += __shfl_xor(lsum, d); csum += __shfl_xor(csum, d); }
    const float mT = m0 + lsum + csum;
    float val_ = (tid < 32) ? (mT + __logf(vp) + et[j]) : NEG_INF;
    float mm = val_;
#pragma unroll
    for (int d = 32; d; d >>= 1) mm = fmaxf(mm, __shfl_xor(mm, d));
    float ee = __expf(val_ - mm);
#pragma unroll
    for (int d = 32; d; d >>= 1) ee += __shfl_xor(ee, d);
    const float logZ = mm + __logf(ee);
    float sc = 0.f, msf = 0.f;
#pragma unroll
    for (int kk = 0; kk < 8; ++kk) {
      const int t = tid + kk * 64;
      const float mf = (float)mk_sh[t];
      const int tg = tgt[b * T_ + t];
      msf += mf;
      float contrib = 0.f;
      if (t >= 1) contrib += trans[tgt[b * T_ + t - 1] * C_ + tg];
      if (t <= T_ - 2) contrib += L[t * C_ + tg];
      sc = fmaf(mf, contrib, sc);
    }
#pragma unroll
    for (int d = 32; d; d >>= 1) { sc += __shfl_xor(sc, d); msf += __shfl_xor(msf, d); }
    if (tid == 0) {
      int last_idx = (int)msf - 1;
      if (last_idx < 0) last_idx = 0;
      const int lt = tgt[b * T_ + last_idx];
      float s = sc + st[tgt[b * T_]] + et[lt];
      s = fmaf((float)mk_sh[T_ - 1], L[(T_ - 1) * C_ + lt], s);
      wsp[b] = logZ;
      wsp[64 + b] = s;
      wsp[128 + b] = msf;
    }
  } else {
    // ========== Viterbi: values-only pure-VALU serial + parallel bp =========
    float TT2[32];
#pragma unroll
    for (int r = 0; r < 32; ++r) TT2[r] = trans[(j ^ MU[r]) * C_ + j];
    float vdj = st[j] + Lc[0];
    dsh[(size_t)0 * C_ + j] = vdj;     // ring row 0 = delta_0 (dup write, same value)

    // R8-validated parallel bp recompute: 2 t per iteration via h; original
    // index order, descending '>=' scan == np.argmax first-index ties.
    auto phase2 = [&](int tb) {
      float TTo[32];
#pragma unroll
      for (int i = 0; i < 32; ++i) TTo[i] = trans[i * C_ + j];
#pragma unroll 2
      for (int it = 0; it < 128; ++it) {
        const int t = tb + 2 * it + h;
        if (t < T_) {
          const float* dr = &dsh[((t - 1) & 255) * C_];
          float best; int idx;
          {
            float4 q = *(const float4*)&dr[28];
            best = q.w + TTo[31]; idx = 31;
            float cx = q.z + TTo[30]; bool ge = cx >= best; best = ge ? cx : best; idx = ge ? 30 : idx;
            cx = q.y + TTo[29]; ge = cx >= best; best = ge ? cx : best; idx = ge ? 29 : idx;
            cx = q.x + TTo[28]; ge = cx >= best; best = ge ? cx : best; idx = ge ? 28 : idx;
          }
#pragma unroll
          for (int g = 6; g >= 0; --g) {
            float4 q = *(const float4*)&dr[4 * g];
            float cx = q.w + TTo[4 * g + 3]; bool ge = cx >= best; best = ge ? cx : best; idx = ge ? 4 * g + 3 : idx;
            cx = q.z + TTo[4 * g + 2]; ge = cx >= best; best = ge ? cx : best; idx = ge ? 4 * g + 2 : idx;
            cx = q.y + TTo[4 * g + 1]; ge = cx >= best; best = ge ? cx : best; idx = ge ? 4 * g + 1 : idx;
            cx = q.x + TTo[4 * g + 0]; ge = cx >= best; best = ge ? cx : best; idx = ge ? 4 * g + 0 : idx;
          }
          const int bpv = (mk_sh[t] > 0) ? idx : j;
          bp[(t - 1) * C_ + j] = (unsigned char)bpv;
        }
      }
    };

    for (int c = 0; c < 32; ++c) {
      int Mc[16];
#pragma unroll
      for (int i = 0; i < 16; ++i) Mc[i] = mk_sh[c * 16 + i];  // off-chain copy
      if (c < 31) {
#pragma unroll
        for (int i = 0; i < 16; ++i) Ln[i] = L[((c + 1) * 16 + i) * C_ + j];
      }
#pragma unroll
      for (int i = 0; i < 16; ++i) {
        if (i == 0 && c == 0) continue;          // t=0 is the init
        const int t = c * 16 + i;
        const int mc = Mc[i];
        float val[32];
        BFLY(vdj, val);
        // candidate SET == np's inner[:,j] bitwise (plain f32 adds); fmax is
        // exactly associative -> bit-exact max in register order.
        float gm0 = fmaxf(fmaxf(val[0] + TT2[0], val[1] + TT2[1]),
                          fmaxf(val[2] + TT2[2], val[3] + TT2[3]));
        float gm1 = fmaxf(fmaxf(val[4] + TT2[4], val[5] + TT2[5]),
                          fmaxf(val[6] + TT2[6], val[7] + TT2[7]));
        float gm2 = fmaxf(fmaxf(val[8] + TT2[8], val[9] + TT2[9]),
                          fmaxf(val[10] + TT2[10], val[11] + TT2[11]));
        float gm3 = fmaxf(fmaxf(val[12] + TT2[12], val[13] + TT2[13]),
                          fmaxf(val[14] + TT2[14], val[15] + TT2[15]));
        float gm4 = fmaxf(fmaxf(val[16] + TT2[16], val[17] + TT2[17]),
                          fmaxf(val[18] + TT2[18], val[19] + TT2[19]));
        float gm5 = fmaxf(fmaxf(val[20] + TT2[20], val[21] + TT2[21]),
                          fmaxf(val[22] + TT2[22], val[23] + TT2[23]));
        float gm6 = fmaxf(fmaxf(val[24] + TT2[24], val[25] + TT2[25]),
                          fmaxf(val[26] + TT2[26], val[27] + TT2[27]));
        float gm7 = fmaxf(fmaxf(val[28] + TT2[28], val[29] + TT2[29]),
                          fmaxf(val[30] + TT2[30], val[31] + TT2[31]));
        const float bestv = fmaxf(fmaxf(fmaxf(gm0, gm1), fmaxf(gm2, gm3)),
                                  fmaxf(fmaxf(gm4, gm5), fmaxf(gm6, gm7)));
        vdj = (mc > 0) ? (bestv + Lc[i]) : vdj;  // f32 add: matches np best+lt
        dsh[(t & 255) * C_ + j] = vdj;           // fire-and-forget ring write
      }
      if (c < 31) {
#pragma unroll
        for (int i = 0; i < 16; ++i) Lc[i] = Ln[i];
      }
      if (c == 15) phase2(1);    // bp for t=1..256 from ring rows 0..255
    }
    phase2(257);                 // bp for t=257..511 (rows hold delta_256..510)

    // final argmax (first-index tie-break) + path score — f32 elementwise
    float fv = (tid < 32) ? (vdj + et[j]) : NEG_INF;
    int fi = (tid < 32) ? j : 64;
#pragma unroll
    for (int d = 32; d; d >>= 1) {
      const float ov = __shfl_xor(fv, d);
      const int oi = __shfl_xor(fi, d);
      if (ov > fv || (ov == fv && oi < fi)) { fv = ov; fi = oi; }
    }
    const int last_tag = fi;
    if (tid == 0) path_out[b] = fv;
    // ---- backtrace: 8-step jump maps (validated) ----
    int cur[32];
#pragma unroll
    for (int e = 0; e < 32; ++e) cur[e] = (tid + 64 * e) & 31;
#pragma unroll
    for (int s = 0; s < 8; ++s) {
#pragma unroll
      for (int e = 0; e < 32; ++e) {
        const int m = (tid + 64 * e) >> 5;
        const int r = 8 * m + 7 - s;
        if (r <= T_ - 2) cur[e] = bp[r * C_ + cur[e]];
      }
    }
#pragma unroll
    for (int e = 0; e < 32; ++e) c8[tid + 64 * e] = (unsigned char)cur[e];
    if (tid == 0) {
      int c = last_tag;
      tagb[T_ - 1] = (unsigned char)c;
      for (int m = 63; m >= 0; --m) { c = c8[m * C_ + c]; btag[m] = c; }  // btag[m]=tag_{8m}
    }
    {
      const int m = tid;
      const int rhi = (m == 63) ? (T_ - 2) : (8 * m + 7);
      int c = (m == 63) ? last_tag : btag[m + 1];
#pragma unroll
      for (int s = 0; s < 7; ++s) {
        const int r = rhi - s;
        if (r >= 8 * m + 1) { c = bp[r * C_ + c]; tagb[r] = (unsigned char)c; }
      }
      tagb[8 * m] = (unsigned char)btag[m];
    }
#pragma unroll
    for (int kk = 0; kk < 8; ++kk) {
      const int t = tid + kk * 64;
      tags_out[b * T_ + t] = (float)tagb[t];
    }
  }
}

// ---------------- loss reduction ----------------
__global__ __launch_bounds__(64) void k_loss(const float* __restrict__ wsp, float* __restrict__ out0) {
  const int tid = threadIdx.x;
  float d = wsp[64 + tid] - wsp[tid];
  float m = wsp[128 + tid];
#pragma unroll
  for (int s = 32; s; s >>= 1) { d += __shfl_xor(d, s); m += __shfl_xor(m, s); }
  if (tid == 0) out0[0] = -d / m;
}

extern "C" void kernel_launch(void* const* d_in, const int* in_sizes, int n_in,
                              void* d_out, int out_size, void* d_ws, size_t ws_size,
                              hipStream_t stream) {
  (void)in_sizes; (void)n_in; (void)out_size; (void)ws_size;
  const float* vec  = (const float*)d_in[0];
  const int* mask   = (const int*)d_in[1];
  const int* tgt    = (const int*)d_in[2];
  const float* W    = (const float*)d_in[3];
  const float* bias = (const float*)d_in[4];
  const float* tr   = (const float*)d_in[5];
  const float* st   = (const float*)d_in[6];
  const float* et   = (const float*)d_in[7];
  float* out = (float*)d_out;
  float* logits = out + 1;
  float* tags = out + 1 + (size_t)B_ * T_ * C_;
  float* path = tags + (size_t)B_ * T_;
  float* wsp = (float*)d_ws;  // [0,64): logZ  [64,128): score  [128,192): mask-sum

  hipLaunchKernelGGL(k_logits, dim3(512), dim3(256), 0, stream, vec, W, bias, logits);
  hipLaunchKernelGGL(k_crf, dim3(128), dim3(64), 0, stream, logits, mask, tgt, tr, st, et, wsp, tags, path);
  hipLaunchKernelGGL(k_loss, dim3(1), dim3(64), 0, stream, wsp, out);
}